// Round 6
// baseline (502.456 us; speedup 1.0000x reference)
//
#include <hip/hip_runtime.h>
#include <hip/hip_bf16.h>
#include <math.h>

#define LEAKY(x) ((x) >= 0.0f ? (x) : 0.2f * (x))

typedef __attribute__((ext_vector_type(8))) short short8;
typedef __attribute__((ext_vector_type(4))) float f32x4;

__device__ __forceinline__ float bf_lo(uint32_t u) { return __uint_as_float(u << 16); }
__device__ __forceinline__ float bf_hi(uint32_t u) { return __uint_as_float(u & 0xffff0000u); }
__device__ __forceinline__ uint32_t pack2(float a, float b) {
    __hip_bfloat162 h = __float22bfloat162_rn(make_float2(a, b));
    return *reinterpret_cast<uint32_t*>(&h);
}

// ---------------------------------------------------------------------------
// w_prep: pack W (f32 [128 k][128 col]) into bf16 MFMA B-fragment order.
// ---------------------------------------------------------------------------
__global__ __launch_bounds__(256) void w_prep(
    const float* __restrict__ W, uint32_t* __restrict__ Wp)
{
    const int slot = blockIdx.x * 256 + threadIdx.x;
    if (slot >= 2048) return;
    const int kb = slot >> 9;
    const int cb = (slot >> 6) & 7;
    const int l  = slot & 63;
    const int k0 = kb * 32 + (l >> 4) * 8;
    const int col = cb * 16 + (l & 15);
    uint32_t u[4];
    #pragma unroll
    for (int p = 0; p < 4; ++p) {
        const float a = W[(size_t)(k0 + 2 * p) * 128 + col];
        const float b = W[(size_t)(k0 + 2 * p + 1) * 128 + col];
        u[p] = pack2(a, b);
    }
    *(uint4*)&Wp[(size_t)slot * 4] = make_uint4(u[0], u[1], u[2], u[3]);
}

// ---------------------------------------------------------------------------
// Kernel 1 (fused): blocks [0, gemmBlocks): MFMA GEMM, 64 nodes/block;
// blocks [gemmBlocks, ...): target histogram.
// ---------------------------------------------------------------------------
__global__ __launch_bounds__(256) void gemm_hist(
    const float* __restrict__ x, const uint32_t* __restrict__ Wp,
    const float* __restrict__ aks, const float* __restrict__ akn,
    uint32_t* __restrict__ xpb, float* __restrict__ attn_self,
    float* __restrict__ attn_nei, const int* __restrict__ ei,
    int* __restrict__ counts, int gemmBlocks, int N, int E)
{
    if (blockIdx.x >= gemmBlocks) {           // histogram part
        const int i = (blockIdx.x - gemmBlocks) * 256 + threadIdx.x;
        if (i < E) atomicAdd(&counts[ei[2 * (size_t)i + 1]], 1);
        return;
    }

    __shared__ float xs[64][132];
    const int t  = threadIdx.x;
    const int w  = t >> 6;
    const int l  = t & 63;
    const int nb = blockIdx.x * 64;

    const int row  = nb + w * 16 + (l & 15);
    const int rowc = min(row, N - 1);
    const int kg   = (l >> 4) * 8;
    const float* xrow = x + (size_t)rowc * 128 + kg;

    f32x4 acc[8] = {};
    #pragma unroll
    for (int kb = 0; kb < 4; ++kb) {
        const float4 x0 = *(const float4*)(xrow + kb * 32);
        const float4 x1 = *(const float4*)(xrow + kb * 32 + 4);
        union { short8 s; uint32_t u[4]; } A;
        A.u[0] = pack2(x0.x, x0.y); A.u[1] = pack2(x0.z, x0.w);
        A.u[2] = pack2(x1.x, x1.y); A.u[3] = pack2(x1.z, x1.w);
        #pragma unroll
        for (int cb = 0; cb < 8; ++cb) {
            union { short8 s; uint4 u; } B;
            B.u = *(const uint4*)&Wp[(((size_t)(kb * 8 + cb)) * 64 + l) * 4];
            acc[cb] = __builtin_amdgcn_mfma_f32_16x16x32_bf16(A.s, B.s, acc[cb], 0, 0, 0);
        }
    }

    const int r0 = (l >> 4) * 4;
    const int cl = l & 15;
    #pragma unroll
    for (int cb = 0; cb < 8; ++cb)
        #pragma unroll
        for (int r = 0; r < 4; ++r)
            xs[w * 16 + r0 + r][cb * 16 + cl] = acc[cb][r];
    __syncthreads();

    #pragma unroll
    for (int i = 0; i < 16; ++i) {
        const int idx = t + i * 256;           // 0..4095
        const int n = idx >> 6, q = idx & 63;
        const int gn = nb + n;
        if (gn < N)
            xpb[(size_t)gn * 64 + q] = pack2(xs[n][2 * q], xs[n][2 * q + 1]);
    }

    {
        const int n = t >> 2, h = t & 3;
        const int gn = nb + n;
        if (gn < N) {
            float ss = 0.0f, sn = 0.0f;
            #pragma unroll
            for (int c = 0; c < 32; ++c) {
                const float v = xs[n][h * 32 + c];
                ss = fmaf(v, aks[c * 4 + h], ss);
                sn = fmaf(v, akn[c * 4 + h], sn);
            }
            attn_self[(size_t)gn * 4 + h] = ss;
            attn_nei [(size_t)gn * 4 + h] = sn;
        }
    }
}

// ---------------------------------------------------------------------------
// CSR scan
// ---------------------------------------------------------------------------
__global__ __launch_bounds__(256) void scan1(
    const int* __restrict__ counts, int* __restrict__ offsets,
    int* __restrict__ tileSums, int N)
{
    __shared__ int sdata[256];
    const int t = threadIdx.x;
    const int i0 = blockIdx.x * 1024 + t * 4;
    int v[4];
    #pragma unroll
    for (int k = 0; k < 4; ++k) v[k] = (i0 + k < N) ? counts[i0 + k] : 0;
    v[1] += v[0]; v[2] += v[1]; v[3] += v[2];
    const int tot = v[3];
    sdata[t] = tot;
    __syncthreads();
    for (int d = 1; d < 256; d <<= 1) {
        int add = (t >= d) ? sdata[t - d] : 0;
        __syncthreads();
        sdata[t] += add;
        __syncthreads();
    }
    const int excl = sdata[t] - tot;
    #pragma unroll
    for (int k = 0; k < 4; ++k) {
        int i = i0 + k;
        if (i < N) offsets[i + 1] = excl + v[k];
    }
    if (t == 255) tileSums[blockIdx.x] = sdata[255];
}

__global__ __launch_bounds__(256) void scan2(
    const int* __restrict__ tileSums, int* __restrict__ tileOffs, int numTiles)
{
    __shared__ int s[256];
    const int t = threadIdx.x;
    const int v = (t < numTiles) ? tileSums[t] : 0;
    s[t] = v;
    __syncthreads();
    for (int d = 1; d < 256; d <<= 1) {
        int add = (t >= d) ? s[t - d] : 0;
        __syncthreads();
        s[t] += add;
        __syncthreads();
    }
    if (t < numTiles) tileOffs[t] = s[t] - v;
}

__global__ void scan3(int* __restrict__ offsets, const int* __restrict__ tileOffs, int N)
{
    const int i = blockIdx.x * 256 + threadIdx.x;
    if (i == 0) offsets[0] = 0;
    if (i < N) offsets[i + 1] += tileOffs[i >> 10];
}

// ---------------------------------------------------------------------------
// fill4: XCD-local CSR scatter. Targets partitioned into 8 contiguous
// ranges; per-range chunk queues; blocks drain the queue matching
// blockIdx&7 (likely their XCD) first, then steal from other ranges.
// All writes to one node's CSR segment thus come from (mostly) one XCD ->
// full-line L2 coalescing instead of 64 B random HBM writebacks.
// Correct regardless of the real block->XCD mapping (pure locality hint).
// ---------------------------------------------------------------------------
#define FILL_CS 2048
__global__ __launch_bounds__(256) void fill4(
    const int* __restrict__ ei, const int* __restrict__ offsets,
    int* __restrict__ counts, int* __restrict__ csr_src,
    int* __restrict__ queues, float rscale, int E)
{
    __shared__ int s_chunk;
    const int numChunks = (E + FILL_CS - 1) / FILL_CS;
    const int myr = blockIdx.x & 7;

    for (int rr = 0; rr < 8; ++rr) {
        const int r = (myr + rr) & 7;
        for (;;) {
            if (threadIdx.x == 0) s_chunk = atomicAdd(&queues[r], 1);
            __syncthreads();
            const int chunk = s_chunk;
            __syncthreads();
            if (chunk >= numChunks) break;
            const int base = chunk * FILL_CS;
            const int end  = min(E, base + FILL_CS);
            for (int i = base + threadIdx.x; i < end; i += 256) {
                const int2 e2 = ((const int2*)ei)[i];
                const int tgt = e2.y;
                const int tr  = min(7, (int)((float)tgt * rscale));
                if (tr == r) {
                    const int slot = atomicSub(&counts[tgt], 1) - 1;
                    csr_src[offsets[tgt] + slot] = e2.x;
                }
            }
        }
    }
}

// ---------------------------------------------------------------------------
// Kernel 3: one wave per node; scalar csr_src stream + bf16 xp gathers.
// ---------------------------------------------------------------------------
__global__ __launch_bounds__(256) void aggregate(
    const int* __restrict__ csr_src, const int* __restrict__ offsets,
    const uint32_t* __restrict__ xpb, const float* __restrict__ attn_self,
    const float* __restrict__ attn_nei, const float* __restrict__ bias,
    float* __restrict__ out, float* __restrict__ alpha_out,
    float* __restrict__ inv_arr, int N, int E)
{
    const int lane = threadIdx.x & 63;
    int node = blockIdx.x * 4 + (threadIdx.x >> 6);
    if (node >= N) return;
    node = __builtin_amdgcn_readfirstlane(node);

    const int hL = lane >> 4;
    const int c0 = 2 * lane;

    const float asH = attn_self[(size_t)node * 4 + hL];
    const float anH = attn_nei [(size_t)node * 4 + hL];
    const float eS  = __expf(LEAKY(asH + anH));
    float sumE = eS;
    const uint32_t uS = xpb[(size_t)node * 64 + lane];
    float acc0 = eS * bf_lo(uS), acc1 = eS * bf_hi(uS);

    const int off0 = __builtin_amdgcn_readfirstlane(offsets[node]);
    const int deg  = __builtin_amdgcn_readfirstlane(offsets[node + 1]) - off0;
    const int* srcp = csr_src + off0;

    for (int j = 0; j < deg; j += 4) {
        const int i1 = min(j + 1, deg - 1);
        const int i2 = min(j + 2, deg - 1);
        const int i3 = min(j + 3, deg - 1);
        const int s0 = srcp[j], s1 = srcp[i1], s2 = srcp[i2], s3 = srcp[i3];
        const float a0 = attn_nei[(size_t)s0 * 4 + hL];
        const float a1 = attn_nei[(size_t)s1 * 4 + hL];
        const float a2 = attn_nei[(size_t)s2 * 4 + hL];
        const float a3 = attn_nei[(size_t)s3 * 4 + hL];
        const uint32_t u0 = xpb[(size_t)s0 * 64 + lane];
        const uint32_t u1 = xpb[(size_t)s1 * 64 + lane];
        const uint32_t u2 = xpb[(size_t)s2 * 64 + lane];
        const uint32_t u3 = xpb[(size_t)s3 * 64 + lane];
        const float v0 = __expf(LEAKY(asH + a0));
        const float v1 = (j + 1 < deg) ? __expf(LEAKY(asH + a1)) : 0.0f;
        const float v2 = (j + 2 < deg) ? __expf(LEAKY(asH + a2)) : 0.0f;
        const float v3 = (j + 3 < deg) ? __expf(LEAKY(asH + a3)) : 0.0f;
        sumE += (v0 + v1) + (v2 + v3);
        acc0 = fmaf(v0, bf_lo(u0), acc0); acc1 = fmaf(v0, bf_hi(u0), acc1);
        acc0 = fmaf(v1, bf_lo(u1), acc0); acc1 = fmaf(v1, bf_hi(u1), acc1);
        acc0 = fmaf(v2, bf_lo(u2), acc0); acc1 = fmaf(v2, bf_hi(u2), acc1);
        acc0 = fmaf(v3, bf_lo(u3), acc0); acc1 = fmaf(v3, bf_hi(u3), acc1);
    }

    const float inv = 1.0f / sumE;
    *(float2*)&out[(size_t)node * 128 + c0] =
        make_float2(fmaf(acc0, inv, bias[c0]), fmaf(acc1, inv, bias[c0 + 1]));
    if ((lane & 15) == 0) {
        inv_arr[(size_t)node * 4 + hL] = inv;
        alpha_out[(size_t)(E + node) * 4 + hL] = eS * inv;
    }
}

// ---------------------------------------------------------------------------
// Kernel 4: alpha for the E real edges, coalesced by edge id.
// ---------------------------------------------------------------------------
__global__ __launch_bounds__(256) void alpha_kernel(
    const int* __restrict__ ei, const float* __restrict__ attn_self,
    const float* __restrict__ attn_nei, const float* __restrict__ inv_arr,
    float* __restrict__ alpha_out, int E)
{
    const int i = blockIdx.x * 256 + threadIdx.x;
    if (i >= E) return;
    const int2 e2 = ((const int2*)ei)[i];
    const int src = e2.x, tgt = e2.y;
    const float4 as4 = *(const float4*)&attn_self[(size_t)tgt * 4];
    const float4 an4 = *(const float4*)&attn_nei[(size_t)src * 4];
    const float4 iv4 = *(const float4*)&inv_arr[(size_t)tgt * 4];
    float4 a;
    a.x = __expf(LEAKY(as4.x + an4.x)) * iv4.x;
    a.y = __expf(LEAKY(as4.y + an4.y)) * iv4.y;
    a.z = __expf(LEAKY(as4.z + an4.z)) * iv4.z;
    a.w = __expf(LEAKY(as4.w + an4.w)) * iv4.w;
    *(float4*)&alpha_out[(size_t)i * 4] = a;
}

// ---------------------------------------------------------------------------
extern "C" void kernel_launch(void* const* d_in, const int* in_sizes, int n_in,
                              void* d_out, int out_size, void* d_ws, size_t ws_size,
                              hipStream_t stream)
{
    const float* x    = (const float*)d_in[0];
    const int*   ei   = (const int*)d_in[1];
    const float* W    = (const float*)d_in[2];
    const float* aks  = (const float*)d_in[3];
    const float* akn  = (const float*)d_in[4];
    const float* bias = (const float*)d_in[5];

    const int N = in_sizes[0] / 128;
    const int E = in_sizes[1] / 2;

    float* out       = (float*)d_out;
    float* alpha_out = out + (size_t)N * 128;

    char* p = (char*)d_ws;
    auto alloc = [&](size_t bytes) {
        char* r = p;
        p += (bytes + 255) & ~(size_t)255;
        return r;
    };
    uint32_t* xpb      = (uint32_t*)alloc((size_t)N * 64 * 4);
    uint32_t* Wp       = (uint32_t*)alloc((size_t)2048 * 16);
    float* attn_self   = (float*)alloc((size_t)N * 4 * 4);
    float* attn_nei    = (float*)alloc((size_t)N * 4 * 4);
    float* inv_arr     = (float*)alloc((size_t)N * 4 * 4);
    int*   counts      = (int*)alloc((size_t)N * 4);
    int*   offsets     = (int*)alloc((size_t)(N + 1) * 4);
    int*   csr_src     = (int*)alloc((size_t)E * 4);
    int*   queues      = (int*)alloc(8 * 4);
    const int numTiles = (N + 1023) / 1024;
    int*   tileSums    = (int*)alloc((size_t)numTiles * 4);
    int*   tileOffs    = (int*)alloc((size_t)numTiles * 4);

    hipMemsetAsync(counts, 0, (size_t)N * 4, stream);
    hipMemsetAsync(queues, 0, 8 * 4, stream);

    w_prep<<<8, 256, 0, stream>>>(W, Wp);

    const int gemmBlocks = (N + 63) / 64;
    const int histBlocks = (E + 255) / 256;
    gemm_hist<<<gemmBlocks + histBlocks, 256, 0, stream>>>(
        x, Wp, aks, akn, xpb, attn_self, attn_nei, ei, counts, gemmBlocks, N, E);
    scan1<<<numTiles, 256, 0, stream>>>(counts, offsets, tileSums, N);
    scan2<<<1, 256, 0, stream>>>(tileSums, tileOffs, numTiles);
    scan3<<<(N + 255) / 256, 256, 0, stream>>>(offsets, tileOffs, N);
    fill4<<<2048, 256, 0, stream>>>(ei, offsets, counts, csr_src, queues,
                                    8.0f / (float)N, E);
    aggregate<<<(N + 3) / 4, 256, 0, stream>>>(csr_src, offsets, xpb,
                                               attn_self, attn_nei, bias, out,
                                               alpha_out, inv_arr, N, E);
    alpha_kernel<<<(E + 255) / 256, 256, 0, stream>>>(ei, attn_self, attn_nei,
                                                      inv_arr, alpha_out, E);
}

// Round 7
// 242.532 us; speedup vs baseline: 2.0717x; 2.0717x over previous
//
#include <hip/hip_runtime.h>
#include <hip/hip_bf16.h>
#include <math.h>

#define LEAKY(x) ((x) >= 0.0f ? (x) : 0.2f * (x))

typedef __attribute__((ext_vector_type(8))) short short8;
typedef __attribute__((ext_vector_type(4))) float f32x4;

__device__ __forceinline__ float bf_lo(uint32_t u) { return __uint_as_float(u << 16); }
__device__ __forceinline__ float bf_hi(uint32_t u) { return __uint_as_float(u & 0xffff0000u); }
__device__ __forceinline__ uint32_t pack2(float a, float b) {
    __hip_bfloat162 h = __float22bfloat162_rn(make_float2(a, b));
    return *reinterpret_cast<uint32_t*>(&h);
}

// ---------------------------------------------------------------------------
// w_prep: pack W (f32 [128 k][128 col]) into bf16 MFMA B-fragment order.
// ---------------------------------------------------------------------------
__global__ __launch_bounds__(256) void w_prep(
    const float* __restrict__ W, uint32_t* __restrict__ Wp)
{
    const int slot = blockIdx.x * 256 + threadIdx.x;
    if (slot >= 2048) return;
    const int kb = slot >> 9;
    const int cb = (slot >> 6) & 7;
    const int l  = slot & 63;
    const int k0 = kb * 32 + (l >> 4) * 8;
    const int col = cb * 16 + (l & 15);
    uint32_t u[4];
    #pragma unroll
    for (int p = 0; p < 4; ++p) {
        const float a = W[(size_t)(k0 + 2 * p) * 128 + col];
        const float b = W[(size_t)(k0 + 2 * p + 1) * 128 + col];
        u[p] = pack2(a, b);
    }
    *(uint4*)&Wp[(size_t)slot * 4] = make_uint4(u[0], u[1], u[2], u[3]);
}

// ---------------------------------------------------------------------------
// Kernel 1 (fused): blocks [0, gemmBlocks): MFMA GEMM, 64 nodes/block;
// blocks [gemmBlocks, ...): target histogram.
// ---------------------------------------------------------------------------
__global__ __launch_bounds__(256) void gemm_hist(
    const float* __restrict__ x, const uint32_t* __restrict__ Wp,
    const float* __restrict__ aks, const float* __restrict__ akn,
    uint32_t* __restrict__ xpb, float* __restrict__ attn_self,
    float* __restrict__ attn_nei, const int* __restrict__ ei,
    int* __restrict__ counts, int gemmBlocks, int N, int E)
{
    if (blockIdx.x >= gemmBlocks) {           // histogram part
        const int i = (blockIdx.x - gemmBlocks) * 256 + threadIdx.x;
        if (i < E) atomicAdd(&counts[ei[2 * (size_t)i + 1]], 1);
        return;
    }

    __shared__ float xs[64][132];
    const int t  = threadIdx.x;
    const int w  = t >> 6;
    const int l  = t & 63;
    const int nb = blockIdx.x * 64;

    const int row  = nb + w * 16 + (l & 15);
    const int rowc = min(row, N - 1);
    const int kg   = (l >> 4) * 8;
    const float* xrow = x + (size_t)rowc * 128 + kg;

    f32x4 acc[8] = {};
    #pragma unroll
    for (int kb = 0; kb < 4; ++kb) {
        const float4 x0 = *(const float4*)(xrow + kb * 32);
        const float4 x1 = *(const float4*)(xrow + kb * 32 + 4);
        union { short8 s; uint32_t u[4]; } A;
        A.u[0] = pack2(x0.x, x0.y); A.u[1] = pack2(x0.z, x0.w);
        A.u[2] = pack2(x1.x, x1.y); A.u[3] = pack2(x1.z, x1.w);
        #pragma unroll
        for (int cb = 0; cb < 8; ++cb) {
            union { short8 s; uint4 u; } B;
            B.u = *(const uint4*)&Wp[(((size_t)(kb * 8 + cb)) * 64 + l) * 4];
            acc[cb] = __builtin_amdgcn_mfma_f32_16x16x32_bf16(A.s, B.s, acc[cb], 0, 0, 0);
        }
    }

    const int r0 = (l >> 4) * 4;
    const int cl = l & 15;
    #pragma unroll
    for (int cb = 0; cb < 8; ++cb)
        #pragma unroll
        for (int r = 0; r < 4; ++r)
            xs[w * 16 + r0 + r][cb * 16 + cl] = acc[cb][r];
    __syncthreads();

    #pragma unroll
    for (int i = 0; i < 16; ++i) {
        const int idx = t + i * 256;           // 0..4095
        const int n = idx >> 6, q = idx & 63;
        const int gn = nb + n;
        if (gn < N)
            xpb[(size_t)gn * 64 + q] = pack2(xs[n][2 * q], xs[n][2 * q + 1]);
    }

    {
        const int n = t >> 2, h = t & 3;
        const int gn = nb + n;
        if (gn < N) {
            float ss = 0.0f, sn = 0.0f;
            #pragma unroll
            for (int c = 0; c < 32; ++c) {
                const float v = xs[n][h * 32 + c];
                ss = fmaf(v, aks[c * 4 + h], ss);
                sn = fmaf(v, akn[c * 4 + h], sn);
            }
            attn_self[(size_t)gn * 4 + h] = ss;
            attn_nei [(size_t)gn * 4 + h] = sn;
        }
    }
}

// ---------------------------------------------------------------------------
// CSR scan
// ---------------------------------------------------------------------------
__global__ __launch_bounds__(256) void scan1(
    const int* __restrict__ counts, int* __restrict__ offsets,
    int* __restrict__ tileSums, int N)
{
    __shared__ int sdata[256];
    const int t = threadIdx.x;
    const int i0 = blockIdx.x * 1024 + t * 4;
    int v[4];
    #pragma unroll
    for (int k = 0; k < 4; ++k) v[k] = (i0 + k < N) ? counts[i0 + k] : 0;
    v[1] += v[0]; v[2] += v[1]; v[3] += v[2];
    const int tot = v[3];
    sdata[t] = tot;
    __syncthreads();
    for (int d = 1; d < 256; d <<= 1) {
        int add = (t >= d) ? sdata[t - d] : 0;
        __syncthreads();
        sdata[t] += add;
        __syncthreads();
    }
    const int excl = sdata[t] - tot;
    #pragma unroll
    for (int k = 0; k < 4; ++k) {
        int i = i0 + k;
        if (i < N) offsets[i + 1] = excl + v[k];
    }
    if (t == 255) tileSums[blockIdx.x] = sdata[255];
}

__global__ __launch_bounds__(256) void scan2(
    const int* __restrict__ tileSums, int* __restrict__ tileOffs, int numTiles)
{
    __shared__ int s[256];
    const int t = threadIdx.x;
    const int v = (t < numTiles) ? tileSums[t] : 0;
    s[t] = v;
    __syncthreads();
    for (int d = 1; d < 256; d <<= 1) {
        int add = (t >= d) ? s[t - d] : 0;
        __syncthreads();
        s[t] += add;
        __syncthreads();
    }
    if (t < numTiles) tileOffs[t] = s[t] - v;
}

__global__ void scan3(int* __restrict__ offsets, const int* __restrict__ tileOffs, int N)
{
    const int i = blockIdx.x * 256 + threadIdx.x;
    if (i == 0) offsets[0] = 0;
    if (i < N) offsets[i + 1] += tileOffs[i >> 10];
}

// ---------------------------------------------------------------------------
// Two-level binned CSR scatter. Bucket = tgt >> 8 (256 nodes/bucket).
// Bucket b's stage region starts at offsets[b<<8] (entries), so per-bucket
// cursors init straight from offsets.
// ---------------------------------------------------------------------------
__global__ void cursor_init(const int* __restrict__ offsets,
                            int* __restrict__ cursor, int NB)
{
    const int b = blockIdx.x * 256 + threadIdx.x;
    if (b < NB) cursor[b] = offsets[b << 8];
}

// binA: chunked LDS-histogram append of (src,tgt) pairs into bucket-
// contiguous stage regions. One global atomicAdd per (bucket,chunk);
// appends are ~21 contiguous entries -> near-full-line writes.
#define CHUNK 8192
__global__ __launch_bounds__(256) void binA(
    const int* __restrict__ ei, int* __restrict__ cursor,
    int2* __restrict__ stage, int NB, int E)
{
    __shared__ int lh[512], lb[512];
    const int base = blockIdx.x * CHUNK;
    const int end  = min(E, base + CHUNK);

    for (int i = threadIdx.x; i < NB; i += 256) lh[i] = 0;
    __syncthreads();
    for (int i = base + threadIdx.x; i < end; i += 256)
        atomicAdd(&lh[((const int2*)ei)[i].y >> 8], 1);
    __syncthreads();
    for (int i = threadIdx.x; i < NB; i += 256) {
        const int c = lh[i];
        lb[i] = c ? atomicAdd(&cursor[i], c) : 0;
        lh[i] = 0;
    }
    __syncthreads();
    for (int i = base + threadIdx.x; i < end; i += 256) {
        const int2 e2 = ((const int2*)ei)[i];
        const int b = e2.y >> 8;
        const int slot = atomicAdd(&lh[b], 1);
        stage[lb[b] + slot] = e2;
    }
}

// binB: one block per bucket; scatter stage pairs into final CSR slots.
// All writes to the bucket's ~17 KB csr_src slice come from ONE block
// (one XCD) -> lines fill fast, write back once. Slot assignment via
// LDS per-node down-counters (global counts is read-only here).
__global__ __launch_bounds__(256) void binB(
    const int2* __restrict__ stage, const int* __restrict__ offsets,
    const int* __restrict__ counts, int* __restrict__ csr_src, int N)
{
    __shared__ int lcnt[256], loff[256];
    const int lo = blockIdx.x << 8;
    const int hi = min(N, lo + 256);
    const int nn = hi - lo;
    if (threadIdx.x < nn) {
        lcnt[threadIdx.x] = counts[lo + threadIdx.x];
        loff[threadIdx.x] = offsets[lo + threadIdx.x];
    }
    __syncthreads();
    const int s0 = offsets[lo];
    const int s1 = offsets[hi];
    for (int i = s0 + threadIdx.x; i < s1; i += 256) {
        const int2 e = stage[i];
        const int tl = e.y - lo;
        const int slot = atomicSub(&lcnt[tl], 1) - 1;
        csr_src[loff[tl] + slot] = e.x;
    }
}

// ---------------------------------------------------------------------------
// Kernel 3: one wave per node; scalar csr_src stream + bf16 xp gathers.
// ---------------------------------------------------------------------------
__global__ __launch_bounds__(256) void aggregate(
    const int* __restrict__ csr_src, const int* __restrict__ offsets,
    const uint32_t* __restrict__ xpb, const float* __restrict__ attn_self,
    const float* __restrict__ attn_nei, const float* __restrict__ bias,
    float* __restrict__ out, float* __restrict__ alpha_out,
    float* __restrict__ inv_arr, int N, int E)
{
    const int lane = threadIdx.x & 63;
    int node = blockIdx.x * 4 + (threadIdx.x >> 6);
    if (node >= N) return;
    node = __builtin_amdgcn_readfirstlane(node);

    const int hL = lane >> 4;
    const int c0 = 2 * lane;

    const float asH = attn_self[(size_t)node * 4 + hL];
    const float anH = attn_nei [(size_t)node * 4 + hL];
    const float eS  = __expf(LEAKY(asH + anH));
    float sumE = eS;
    const uint32_t uS = xpb[(size_t)node * 64 + lane];
    float acc0 = eS * bf_lo(uS), acc1 = eS * bf_hi(uS);

    const int off0 = __builtin_amdgcn_readfirstlane(offsets[node]);
    const int deg  = __builtin_amdgcn_readfirstlane(offsets[node + 1]) - off0;
    const int* srcp = csr_src + off0;

    for (int j = 0; j < deg; j += 4) {
        const int i1 = min(j + 1, deg - 1);
        const int i2 = min(j + 2, deg - 1);
        const int i3 = min(j + 3, deg - 1);
        const int s0 = srcp[j], s1 = srcp[i1], s2 = srcp[i2], s3 = srcp[i3];
        const float a0 = attn_nei[(size_t)s0 * 4 + hL];
        const float a1 = attn_nei[(size_t)s1 * 4 + hL];
        const float a2 = attn_nei[(size_t)s2 * 4 + hL];
        const float a3 = attn_nei[(size_t)s3 * 4 + hL];
        const uint32_t u0 = xpb[(size_t)s0 * 64 + lane];
        const uint32_t u1 = xpb[(size_t)s1 * 64 + lane];
        const uint32_t u2 = xpb[(size_t)s2 * 64 + lane];
        const uint32_t u3 = xpb[(size_t)s3 * 64 + lane];
        const float v0 = __expf(LEAKY(asH + a0));
        const float v1 = (j + 1 < deg) ? __expf(LEAKY(asH + a1)) : 0.0f;
        const float v2 = (j + 2 < deg) ? __expf(LEAKY(asH + a2)) : 0.0f;
        const float v3 = (j + 3 < deg) ? __expf(LEAKY(asH + a3)) : 0.0f;
        sumE += (v0 + v1) + (v2 + v3);
        acc0 = fmaf(v0, bf_lo(u0), acc0); acc1 = fmaf(v0, bf_hi(u0), acc1);
        acc0 = fmaf(v1, bf_lo(u1), acc0); acc1 = fmaf(v1, bf_hi(u1), acc1);
        acc0 = fmaf(v2, bf_lo(u2), acc0); acc1 = fmaf(v2, bf_hi(u2), acc1);
        acc0 = fmaf(v3, bf_lo(u3), acc0); acc1 = fmaf(v3, bf_hi(u3), acc1);
    }

    const float inv = 1.0f / sumE;
    *(float2*)&out[(size_t)node * 128 + c0] =
        make_float2(fmaf(acc0, inv, bias[c0]), fmaf(acc1, inv, bias[c0 + 1]));
    if ((lane & 15) == 0) {
        inv_arr[(size_t)node * 4 + hL] = inv;
        alpha_out[(size_t)(E + node) * 4 + hL] = eS * inv;
    }
}

// ---------------------------------------------------------------------------
// Kernel 4: alpha for the E real edges, coalesced by edge id (overwrites
// the stage scratch that lived in this region).
// ---------------------------------------------------------------------------
__global__ __launch_bounds__(256) void alpha_kernel(
    const int* __restrict__ ei, const float* __restrict__ attn_self,
    const float* __restrict__ attn_nei, const float* __restrict__ inv_arr,
    float* __restrict__ alpha_out, int E)
{
    const int i = blockIdx.x * 256 + threadIdx.x;
    if (i >= E) return;
    const int2 e2 = ((const int2*)ei)[i];
    const int src = e2.x, tgt = e2.y;
    const float4 as4 = *(const float4*)&attn_self[(size_t)tgt * 4];
    const float4 an4 = *(const float4*)&attn_nei[(size_t)src * 4];
    const float4 iv4 = *(const float4*)&inv_arr[(size_t)tgt * 4];
    float4 a;
    a.x = __expf(LEAKY(as4.x + an4.x)) * iv4.x;
    a.y = __expf(LEAKY(as4.y + an4.y)) * iv4.y;
    a.z = __expf(LEAKY(as4.z + an4.z)) * iv4.z;
    a.w = __expf(LEAKY(as4.w + an4.w)) * iv4.w;
    *(float4*)&alpha_out[(size_t)i * 4] = a;
}

// ---------------------------------------------------------------------------
extern "C" void kernel_launch(void* const* d_in, const int* in_sizes, int n_in,
                              void* d_out, int out_size, void* d_ws, size_t ws_size,
                              hipStream_t stream)
{
    const float* x    = (const float*)d_in[0];
    const int*   ei   = (const int*)d_in[1];
    const float* W    = (const float*)d_in[2];
    const float* aks  = (const float*)d_in[3];
    const float* akn  = (const float*)d_in[4];
    const float* bias = (const float*)d_in[5];

    const int N = in_sizes[0] / 128;
    const int E = in_sizes[1] / 2;
    const int NB = (N + 255) >> 8;           // buckets of 256 nodes

    float* out       = (float*)d_out;
    float* alpha_out = out + (size_t)N * 128;
    // stage (E x int2 = 8B/edge) overlays the alpha region of d_out
    // (floats [0, 2E)); self-loop alphas live at [4E, 4E+4N) - no overlap.
    // Written by binA, read by binB, overwritten by alpha_kernel.
    int2* stage      = (int2*)alpha_out;

    char* p = (char*)d_ws;
    auto alloc = [&](size_t bytes) {
        char* r = p;
        p += (bytes + 255) & ~(size_t)255;
        return r;
    };
    uint32_t* xpb      = (uint32_t*)alloc((size_t)N * 64 * 4);
    uint32_t* Wp       = (uint32_t*)alloc((size_t)2048 * 16);
    float* attn_self   = (float*)alloc((size_t)N * 4 * 4);
    float* attn_nei    = (float*)alloc((size_t)N * 4 * 4);
    float* inv_arr     = (float*)alloc((size_t)N * 4 * 4);
    int*   counts      = (int*)alloc((size_t)N * 4);
    int*   offsets     = (int*)alloc((size_t)(N + 1) * 4);
    int*   csr_src     = (int*)alloc((size_t)E * 4);
    int*   cursor      = (int*)alloc((size_t)NB * 4);
    const int numTiles = (N + 1023) / 1024;
    int*   tileSums    = (int*)alloc((size_t)numTiles * 4);
    int*   tileOffs    = (int*)alloc((size_t)numTiles * 4);

    hipMemsetAsync(counts, 0, (size_t)N * 4, stream);

    w_prep<<<8, 256, 0, stream>>>(W, Wp);

    const int gemmBlocks = (N + 63) / 64;
    const int histBlocks = (E + 255) / 256;
    gemm_hist<<<gemmBlocks + histBlocks, 256, 0, stream>>>(
        x, Wp, aks, akn, xpb, attn_self, attn_nei, ei, counts, gemmBlocks, N, E);
    scan1<<<numTiles, 256, 0, stream>>>(counts, offsets, tileSums, N);
    scan2<<<1, 256, 0, stream>>>(tileSums, tileOffs, numTiles);
    scan3<<<(N + 255) / 256, 256, 0, stream>>>(offsets, tileOffs, N);
    cursor_init<<<(NB + 255) / 256, 256, 0, stream>>>(offsets, cursor, NB);
    binA<<<(E + CHUNK - 1) / CHUNK, 256, 0, stream>>>(ei, cursor, stage, NB, E);
    binB<<<NB, 256, 0, stream>>>(stage, offsets, counts, csr_src, N);
    aggregate<<<(N + 3) / 4, 256, 0, stream>>>(csr_src, offsets, xpb,
                                               attn_self, attn_nei, bias, out,
                                               alpha_out, inv_arr, N, E);
    alpha_kernel<<<(E + 255) / 256, 256, 0, stream>>>(ei, attn_self, attn_nei,
                                                      inv_arr, alpha_out, E);
}

// Round 8
// 207.321 us; speedup vs baseline: 2.4236x; 1.1698x over previous
//
#include <hip/hip_runtime.h>
#include <hip/hip_bf16.h>
#include <math.h>

#define LEAKY(x) ((x) >= 0.0f ? (x) : 0.2f * (x))
#define CHUNK 8192

typedef __attribute__((ext_vector_type(8))) short short8;
typedef __attribute__((ext_vector_type(4))) float f32x4;

__device__ __forceinline__ float bf_lo(uint32_t u) { return __uint_as_float(u << 16); }
__device__ __forceinline__ float bf_hi(uint32_t u) { return __uint_as_float(u & 0xffff0000u); }
__device__ __forceinline__ uint32_t pack2(float a, float b) {
    __hip_bfloat162 h = __float22bfloat162_rn(make_float2(a, b));
    return *reinterpret_cast<uint32_t*>(&h);
}

// ---------------------------------------------------------------------------
// w_prep: pack W (f32 [128 k][128 col]) into bf16 MFMA B-fragment order.
// ---------------------------------------------------------------------------
__global__ __launch_bounds__(256) void w_prep(
    const float* __restrict__ W, uint32_t* __restrict__ Wp)
{
    const int slot = blockIdx.x * 256 + threadIdx.x;
    if (slot >= 2048) return;
    const int kb = slot >> 9;
    const int cb = (slot >> 6) & 7;
    const int l  = slot & 63;
    const int k0 = kb * 32 + (l >> 4) * 8;
    const int col = cb * 16 + (l & 15);
    uint32_t u[4];
    #pragma unroll
    for (int p = 0; p < 4; ++p) {
        const float a = W[(size_t)(k0 + 2 * p) * 128 + col];
        const float b = W[(size_t)(k0 + 2 * p + 1) * 128 + col];
        u[p] = pack2(a, b);
    }
    *(uint4*)&Wp[(size_t)slot * 4] = make_uint4(u[0], u[1], u[2], u[3]);
}

// ---------------------------------------------------------------------------
// gemm: MFMA xp = bf16(x @ W) + attn_self/attn_neigh. 64 nodes/block.
// ---------------------------------------------------------------------------
__global__ __launch_bounds__(256) void gemm_xp(
    const float* __restrict__ x, const uint32_t* __restrict__ Wp,
    const float* __restrict__ aks, const float* __restrict__ akn,
    uint32_t* __restrict__ xpb, float* __restrict__ attn_self,
    float* __restrict__ attn_nei, int N)
{
    __shared__ float xs[64][133];
    const int t  = threadIdx.x;
    const int w  = t >> 6;
    const int l  = t & 63;
    const int nb = blockIdx.x * 64;

    const int row  = nb + w * 16 + (l & 15);
    const int rowc = min(row, N - 1);
    const int kg   = (l >> 4) * 8;
    const float* xrow = x + (size_t)rowc * 128 + kg;

    f32x4 acc[8] = {};
    #pragma unroll
    for (int kb = 0; kb < 4; ++kb) {
        const float4 x0 = *(const float4*)(xrow + kb * 32);
        const float4 x1 = *(const float4*)(xrow + kb * 32 + 4);
        union { short8 s; uint32_t u[4]; } A;
        A.u[0] = pack2(x0.x, x0.y); A.u[1] = pack2(x0.z, x0.w);
        A.u[2] = pack2(x1.x, x1.y); A.u[3] = pack2(x1.z, x1.w);
        #pragma unroll
        for (int cb = 0; cb < 8; ++cb) {
            union { short8 s; uint4 u; } B;
            B.u = *(const uint4*)&Wp[(((size_t)(kb * 8 + cb)) * 64 + l) * 4];
            acc[cb] = __builtin_amdgcn_mfma_f32_16x16x32_bf16(A.s, B.s, acc[cb], 0, 0, 0);
        }
    }

    // D -> LDS (f32): row = w*16 + (l>>4)*4 + r, col = cb*16 + (l&15)
    const int r0 = (l >> 4) * 4;
    const int cl = l & 15;
    #pragma unroll
    for (int cb = 0; cb < 8; ++cb)
        #pragma unroll
        for (int r = 0; r < 4; ++r)
            xs[w * 16 + r0 + r][cb * 16 + cl] = acc[cb][r];
    __syncthreads();

    // repack 64 nodes x 128 cols -> bf16x2, coalesced
    #pragma unroll
    for (int i = 0; i < 16; ++i) {
        const int idx = t + i * 256;           // 0..4095
        const int n = idx >> 6, q = idx & 63;
        const int gn = nb + n;
        if (gn < N)
            xpb[(size_t)gn * 64 + q] = pack2(xs[n][2 * q], xs[n][2 * q + 1]);
    }

    // attn (wave-major mapping: lane = node, wave = head -> 2-way LDS only)
    {
        const int n = t & 63, h = t >> 6;
        const int gn = nb + n;
        if (gn < N) {
            float ss = 0.0f, sn = 0.0f;
            #pragma unroll
            for (int c = 0; c < 32; ++c) {
                const float v = xs[n][h * 32 + c];
                ss = fmaf(v, aks[c * 4 + h], ss);
                sn = fmaf(v, akn[c * 4 + h], sn);
            }
            attn_self[(size_t)gn * 4 + h] = ss;
            attn_nei [(size_t)gn * 4 + h] = sn;
        }
    }
}

// ---------------------------------------------------------------------------
// binA: per-chunk bucket binning, NO global per-node histogram.
// LDS hist(buckets) -> LDS scan -> bucket-grouped pairs into the chunk's own
// stage region + start_table[(chunk,bucket)] + LDS-aggregated bucket totals.
// ---------------------------------------------------------------------------
__global__ __launch_bounds__(256) void binA(
    const int* __restrict__ ei, int2* __restrict__ stage,
    int* __restrict__ start_table, int* __restrict__ bucket_tot,
    int NB, int E)
{
    __shared__ int lh[512], lex[512], ss[256];
    const int t    = threadIdx.x;
    const int base = blockIdx.x * CHUNK;
    const int end  = min(E, base + CHUNK);

    for (int i = t; i < 512; i += 256) lh[i] = 0;
    __syncthreads();
    for (int i = base + t; i < end; i += 256)
        atomicAdd(&lh[((const int2*)ei)[i].y >> 8], 1);
    __syncthreads();

    // exclusive scan of lh[0..512) -> lex (pair-per-thread Hillis-Steele)
    const int v0 = lh[2 * t], v1 = lh[2 * t + 1];
    ss[t] = v0 + v1;
    __syncthreads();
    for (int d = 1; d < 256; d <<= 1) {
        const int add = (t >= d) ? ss[t - d] : 0;
        __syncthreads();
        ss[t] += add;
        __syncthreads();
    }
    const int ex = ss[t] - v0 - v1;
    lex[2 * t] = ex;
    lex[2 * t + 1] = ex + v0;
    __syncthreads();

    // start_table (NB+1 entries per chunk) + bucket totals
    const size_t cbase = (size_t)blockIdx.x * (NB + 1);
    for (int b = t; b <= NB; b += 256) start_table[cbase + b] = base + lex[b];
    for (int b = t; b < NB; b += 256)
        if (lh[b]) atomicAdd(&bucket_tot[b], lh[b]);
    __syncthreads();

    // place pairs: lex doubles as the running cursor
    for (int i = base + t; i < end; i += 256) {
        const int2 e2 = ((const int2*)ei)[i];
        const int slot = atomicAdd(&lex[e2.y >> 8], 1);
        stage[base + slot] = e2;
    }
}

// ---------------------------------------------------------------------------
// bucket_scan: 1 block; exclusive scan of bucket totals -> bucket_off[0..NB];
// also writes offsets[N] = E.
// ---------------------------------------------------------------------------
__global__ __launch_bounds__(256) void bucket_scan(
    const int* __restrict__ bucket_tot, int* __restrict__ bucket_off,
    int* __restrict__ offsets, int NB, int N, int E)
{
    __shared__ int ss[256];
    const int t = threadIdx.x;
    const int v0 = (2 * t     < NB) ? bucket_tot[2 * t]     : 0;
    const int v1 = (2 * t + 1 < NB) ? bucket_tot[2 * t + 1] : 0;
    ss[t] = v0 + v1;
    __syncthreads();
    for (int d = 1; d < 256; d <<= 1) {
        const int add = (t >= d) ? ss[t - d] : 0;
        __syncthreads();
        ss[t] += add;
        __syncthreads();
    }
    const int ex = ss[t] - v0 - v1;
    if (2 * t     <= NB) bucket_off[2 * t]     = ex;
    if (2 * t + 1 <= NB) bucket_off[2 * t + 1] = ex + v0;
    if (t == 0) offsets[N] = E;
}

// ---------------------------------------------------------------------------
// binB: one block per bucket (256 nodes). Flattens its 204 chunk-ranges via
// LDS prefix + binary search; per-node counts/scan/scatter all in LDS; writes
// offsets[lo..hi) and csr_src — single-XCD write locality for both.
// ---------------------------------------------------------------------------
__global__ __launch_bounds__(256) void binB(
    const int2* __restrict__ stage, const int* __restrict__ start_table,
    const int* __restrict__ bucket_off, int* __restrict__ offsets,
    int* __restrict__ csr_src, int nc, int NB, int N)
{
    __shared__ int s0[256], cum[257], ss[256], lcnt[256], lcur[256];
    const int t  = threadIdx.x;
    const int b  = blockIdx.x;
    const int lo = b << 8;
    const int nn = min(N, lo + 256) - lo;

    int len = 0;
    if (t < nc) {
        const size_t cb = (size_t)t * (NB + 1);
        const int a0 = start_table[cb + b];
        s0[t] = a0;
        len   = start_table[cb + b + 1] - a0;
    }
    ss[t] = len;
    lcnt[t] = 0;
    __syncthreads();
    for (int d = 1; d < 256; d <<= 1) {
        const int add = (t >= d) ? ss[t - d] : 0;
        __syncthreads();
        ss[t] += add;
        __syncthreads();
    }
    if (t == 0) cum[0] = 0;
    cum[t + 1] = ss[t];
    __syncthreads();
    const int T = cum[nc];

    // pass 1: per-node counts
    for (int g = t; g < T; g += 256) {
        int loc = 0, hic = nc - 1;
        while (loc < hic) {
            const int mid = (loc + hic + 1) >> 1;
            if (cum[mid] <= g) loc = mid; else hic = mid - 1;
        }
        const int2 e = stage[s0[loc] + (g - cum[loc])];
        atomicAdd(&lcnt[e.y - lo], 1);
    }
    __syncthreads();

    // scan per-node counts -> global offsets + scatter cursors
    const int v = lcnt[t];
    ss[t] = v;
    __syncthreads();
    for (int d = 1; d < 256; d <<= 1) {
        const int add = (t >= d) ? ss[t - d] : 0;
        __syncthreads();
        ss[t] += add;
        __syncthreads();
    }
    const int nodeoff = bucket_off[b] + ss[t] - v;
    lcur[t] = nodeoff;
    if (t < nn) offsets[lo + t] = nodeoff;
    __syncthreads();

    // pass 2: scatter src ids into final CSR slots
    for (int g = t; g < T; g += 256) {
        int loc = 0, hic = nc - 1;
        while (loc < hic) {
            const int mid = (loc + hic + 1) >> 1;
            if (cum[mid] <= g) loc = mid; else hic = mid - 1;
        }
        const int2 e = stage[s0[loc] + (g - cum[loc])];
        const int slot = atomicAdd(&lcur[e.y - lo], 1);
        csr_src[slot] = e.x;
    }
}

// ---------------------------------------------------------------------------
// aggregate: one wave per node; scalar csr_src stream + bf16 xp gathers.
// ---------------------------------------------------------------------------
__global__ __launch_bounds__(256) void aggregate(
    const int* __restrict__ csr_src, const int* __restrict__ offsets,
    const uint32_t* __restrict__ xpb, const float* __restrict__ attn_self,
    const float* __restrict__ attn_nei, const float* __restrict__ bias,
    float* __restrict__ out, float* __restrict__ alpha_out,
    float* __restrict__ inv_arr, int N, int E)
{
    const int lane = threadIdx.x & 63;
    int node = blockIdx.x * 4 + (threadIdx.x >> 6);
    if (node >= N) return;
    node = __builtin_amdgcn_readfirstlane(node);

    const int hL = lane >> 4;
    const int c0 = 2 * lane;

    const float asH = attn_self[(size_t)node * 4 + hL];
    const float anH = attn_nei [(size_t)node * 4 + hL];
    const float eS  = __expf(LEAKY(asH + anH));
    float sumE = eS;
    const uint32_t uS = xpb[(size_t)node * 64 + lane];
    float acc0 = eS * bf_lo(uS), acc1 = eS * bf_hi(uS);

    const int off0 = __builtin_amdgcn_readfirstlane(offsets[node]);
    const int deg  = __builtin_amdgcn_readfirstlane(offsets[node + 1]) - off0;
    const int* srcp = csr_src + off0;

    for (int j = 0; j < deg; j += 4) {
        const int i1 = min(j + 1, deg - 1);
        const int i2 = min(j + 2, deg - 1);
        const int i3 = min(j + 3, deg - 1);
        const int s0 = srcp[j], s1 = srcp[i1], s2 = srcp[i2], s3 = srcp[i3];
        const float a0 = attn_nei[(size_t)s0 * 4 + hL];
        const float a1 = attn_nei[(size_t)s1 * 4 + hL];
        const float a2 = attn_nei[(size_t)s2 * 4 + hL];
        const float a3 = attn_nei[(size_t)s3 * 4 + hL];
        const uint32_t u0 = xpb[(size_t)s0 * 64 + lane];
        const uint32_t u1 = xpb[(size_t)s1 * 64 + lane];
        const uint32_t u2 = xpb[(size_t)s2 * 64 + lane];
        const uint32_t u3 = xpb[(size_t)s3 * 64 + lane];
        const float v0 = __expf(LEAKY(asH + a0));
        const float v1 = (j + 1 < deg) ? __expf(LEAKY(asH + a1)) : 0.0f;
        const float v2 = (j + 2 < deg) ? __expf(LEAKY(asH + a2)) : 0.0f;
        const float v3 = (j + 3 < deg) ? __expf(LEAKY(asH + a3)) : 0.0f;
        sumE += (v0 + v1) + (v2 + v3);
        acc0 = fmaf(v0, bf_lo(u0), acc0); acc1 = fmaf(v0, bf_hi(u0), acc1);
        acc0 = fmaf(v1, bf_lo(u1), acc0); acc1 = fmaf(v1, bf_hi(u1), acc1);
        acc0 = fmaf(v2, bf_lo(u2), acc0); acc1 = fmaf(v2, bf_hi(u2), acc1);
        acc0 = fmaf(v3, bf_lo(u3), acc0); acc1 = fmaf(v3, bf_hi(u3), acc1);
    }

    const float inv = 1.0f / sumE;
    *(float2*)&out[(size_t)node * 128 + c0] =
        make_float2(fmaf(acc0, inv, bias[c0]), fmaf(acc1, inv, bias[c0 + 1]));
    if ((lane & 15) == 0) {
        inv_arr[(size_t)node * 4 + hL] = inv;
        alpha_out[(size_t)(E + node) * 4 + hL] = eS * inv;
    }
}

// ---------------------------------------------------------------------------
// alpha for the E real edges, coalesced by edge id (overwrites stage scratch).
// ---------------------------------------------------------------------------
__global__ __launch_bounds__(256) void alpha_kernel(
    const int* __restrict__ ei, const float* __restrict__ attn_self,
    const float* __restrict__ attn_nei, const float* __restrict__ inv_arr,
    float* __restrict__ alpha_out, int E)
{
    const int i = blockIdx.x * 256 + threadIdx.x;
    if (i >= E) return;
    const int2 e2 = ((const int2*)ei)[i];
    const int src = e2.x, tgt = e2.y;
    const float4 as4 = *(const float4*)&attn_self[(size_t)tgt * 4];
    const float4 an4 = *(const float4*)&attn_nei[(size_t)src * 4];
    const float4 iv4 = *(const float4*)&inv_arr[(size_t)tgt * 4];
    float4 a;
    a.x = __expf(LEAKY(as4.x + an4.x)) * iv4.x;
    a.y = __expf(LEAKY(as4.y + an4.y)) * iv4.y;
    a.z = __expf(LEAKY(as4.z + an4.z)) * iv4.z;
    a.w = __expf(LEAKY(as4.w + an4.w)) * iv4.w;
    *(float4*)&alpha_out[(size_t)i * 4] = a;
}

// ---------------------------------------------------------------------------
extern "C" void kernel_launch(void* const* d_in, const int* in_sizes, int n_in,
                              void* d_out, int out_size, void* d_ws, size_t ws_size,
                              hipStream_t stream)
{
    const float* x    = (const float*)d_in[0];
    const int*   ei   = (const int*)d_in[1];
    const float* W    = (const float*)d_in[2];
    const float* aks  = (const float*)d_in[3];
    const float* akn  = (const float*)d_in[4];
    const float* bias = (const float*)d_in[5];

    const int N  = in_sizes[0] / 128;
    const int E  = in_sizes[1] / 2;
    const int NB = (N + 255) >> 8;            // buckets of 256 nodes
    const int nc = (E + CHUNK - 1) / CHUNK;   // chunks (<= 256 for this E)

    float* out       = (float*)d_out;
    float* alpha_out = out + (size_t)N * 128;
    // stage (E x int2 = 8B/edge) overlays the alpha region of d_out (floats
    // [0, 2E)); self-loop alphas live at [4E, ...) - no overlap. Written by
    // binA, read by binB, overwritten by alpha_kernel at the end.
    int2* stage      = (int2*)alpha_out;

    char* p = (char*)d_ws;
    auto alloc = [&](size_t bytes) {
        char* r = p;
        p += (bytes + 255) & ~(size_t)255;
        return r;
    };
    uint32_t* xpb       = (uint32_t*)alloc((size_t)N * 64 * 4);
    uint32_t* Wp        = (uint32_t*)alloc((size_t)2048 * 16);
    float* attn_self    = (float*)alloc((size_t)N * 4 * 4);
    float* attn_nei     = (float*)alloc((size_t)N * 4 * 4);
    float* inv_arr      = (float*)alloc((size_t)N * 4 * 4);
    int*   offsets      = (int*)alloc((size_t)(N + 1) * 4);
    int*   csr_src      = (int*)alloc((size_t)E * 4);
    int*   bucket_tot   = (int*)alloc((size_t)NB * 4);
    int*   bucket_off   = (int*)alloc((size_t)(NB + 1) * 4);
    int*   start_table  = (int*)alloc((size_t)nc * (NB + 1) * 4);

    hipMemsetAsync(bucket_tot, 0, (size_t)NB * 4, stream);

    w_prep<<<8, 256, 0, stream>>>(W, Wp);
    gemm_xp<<<(N + 63) / 64, 256, 0, stream>>>(x, Wp, aks, akn, xpb,
                                               attn_self, attn_nei, N);
    binA<<<nc, 256, 0, stream>>>(ei, stage, start_table, bucket_tot, NB, E);
    bucket_scan<<<1, 256, 0, stream>>>(bucket_tot, bucket_off, offsets, NB, N, E);
    binB<<<NB, 256, 0, stream>>>(stage, start_table, bucket_off, offsets,
                                 csr_src, nc, NB, N);
    aggregate<<<(N + 3) / 4, 256, 0, stream>>>(csr_src, offsets, xpb,
                                               attn_self, attn_nei, bias, out,
                                               alpha_out, inv_arr, N, E);
    alpha_kernel<<<(E + 255) / 256, 256, 0, stream>>>(ei, attn_self, attn_nei,
                                                      inv_arr, alpha_out, E);
}